// Round 9
// baseline (351.960 us; speedup 1.0000x reference)
//
#include <hip/hip_runtime.h>
#include <math.h>

#define N_NODES 50000
#define E_EDGES 800000
#define FIN     128
#define HC1     256   // H*C = 4*64
#define C2      64
#define NGRAPH  8
#define LOG2E   1.4426950408889634f
#define NG1     391    // gemm1 blocks
#define NSCAT   3125   // scatter/count blocks: E/256
#define NBKT    8
#define BSTRIDE 50176  // padded per-bucket stride (ints)
#define PWAVES  8192   // persistent waves (2048 blocks x 4)

typedef short  s16x8 __attribute__((ext_vector_type(8)));
typedef float  f32x4 __attribute__((ext_vector_type(4)));
typedef _Float16 h2  __attribute__((ext_vector_type(2)));

__device__ __forceinline__ unsigned short f2bf(float f) {
  union { float f; unsigned u; } v; v.f = f;
  unsigned r = v.u + 0x7FFFu + ((v.u >> 16) & 1u);  // RNE
  return (unsigned short)(r >> 16);
}
__device__ __forceinline__ h2 bch2(unsigned u) { return __builtin_bit_cast(h2, u); }
__device__ __forceinline__ unsigned short f2h(float f) {
  _Float16 h = (_Float16)f;
  return __builtin_bit_cast(unsigned short, h);
}

__device__ __forceinline__ float fdot2f(h2 a, h2 b, float c) {
#if __has_builtin(__builtin_amdgcn_fdot2)
  return __builtin_amdgcn_fdot2(a, b, c, false);
#else
  return c + (float)a[0] * (float)b[0] + (float)a[1] * (float)b[1];
#endif
}

// leaky_relu in packed f16: max(e, 0.2*e) exact for both signs.
__device__ __forceinline__ h2 leaky2(h2 e) {
  const h2 c02 = {(_Float16)0.2f, (_Float16)0.2f};
  return __builtin_elementwise_max(e, e * c02);
}

// ---------------------- prep: weight transpose+cast  ||  bucketed degree count
__global__ __launch_bounds__(256) void prep_kernel(
    const float* __restrict__ Wl1, const float* __restrict__ Wr1,
    const float* __restrict__ Wl2, const float* __restrict__ Wr2,
    unsigned short* __restrict__ Bt1, unsigned short* __restrict__ Bt2,
    const int* __restrict__ edst, int* __restrict__ deg8) {
  const int b = blockIdx.x;
  if (b < 384) {
    const int idx = b * 256 + threadIdx.x;
    if (idx < 512 * 128) {            // Bt1 [512][128] from [128][256] pair
      const int n = idx >> 7, k = idx & 127;
      const float* B = (n < 256) ? Wl1 : Wr1;
      const int nn = (n < 256) ? n : n - 256;
      Bt1[idx] = f2bf(B[k * 256 + nn]);
    } else {                          // Bt2 [128][256] from [256][64] pair
      const int t = idx - 512 * 128;
      const int n = t >> 8, k = t & 255;
      const float* B = (n < 64) ? Wl2 : Wr2;
      const int nn = (n < 64) ? n : n - 64;
      Bt2[t] = f2bf(B[k * 64 + nn]);
    }
  } else {
    const int eblk = b - 384;
    const int e = eblk * 256 + threadIdx.x;
    if (e < E_EDGES)
      atomicAdd(&deg8[(eblk & 7) * BSTRIDE + edst[e]], 1);
  }
}

// ------------------------------------------------------------- CSR scan
// scan1: per-node total over 8 buckets -> block-level inclusive scan
__global__ __launch_bounds__(1024) void scan1(const int* __restrict__ deg8, int N,
                                              int* __restrict__ incl, int* __restrict__ bsum) {
  __shared__ int sd[1024];
  const int tid = threadIdx.x;
  const int i = blockIdx.x * 1024 + tid;
  int tot = 0;
  if (i < N) {
#pragma unroll
    for (int bk = 0; bk < NBKT; bk++) tot += deg8[bk * BSTRIDE + i];
  }
  sd[tid] = tot;
  __syncthreads();
  for (int off = 1; off < 1024; off <<= 1) {
    int t = 0;
    if (tid >= off) t = sd[tid - off];
    __syncthreads();
    if (tid >= off) sd[tid] += t;
    __syncthreads();
  }
  incl[i] = sd[tid];
  if (tid == 1023) bsum[blockIdx.x] = sd[1023];
}

// scan3: apply block prefix; emit offs + per-bucket cursors
__global__ __launch_bounds__(256) void scan3(
    const int* __restrict__ deg8, const int* __restrict__ incl,
    const int* __restrict__ bsum, int nb, int N,
    int* __restrict__ offs, int* __restrict__ cursor8) {
  __shared__ int pb[64];
  if (threadIdx.x < 64) {
    const int lane = threadIdx.x;
    const int orig = (lane < nb) ? bsum[lane] : 0;
    int v = orig;
    for (int off = 1; off < 64; off <<= 1) {
      int t = __shfl_up(v, off);
      if (lane >= off) v += t;
    }
    pb[lane] = v - orig;  // exclusive
  }
  __syncthreads();
  const int i = blockIdx.x * 256 + threadIdx.x;
  if (i >= N) return;
  const int val = incl[i] + pb[i >> 10];   // inclusive total scan
  offs[i + 1] = val;
  if (i == 0) offs[0] = 0;
  int d8[NBKT];
  int tot = 0;
#pragma unroll
  for (int bk = 0; bk < NBKT; bk++) { d8[bk] = deg8[bk * BSTRIDE + i]; tot += d8[bk]; }
  int base = val - tot;
#pragma unroll
  for (int bk = 0; bk < NBKT; bk++) { cursor8[bk * BSTRIDE + i] = base; base += d8[bk]; }
}

// --------------------- fused: GEMM1 (x[N,128]->xlr1[N,512])  ||  edge scatter
__global__ __launch_bounds__(256) void gemm1_scatter(
    const float* __restrict__ A, const unsigned short* __restrict__ Bt,
    unsigned short* __restrict__ Cc,
    const int* __restrict__ esrc_in, const int* __restrict__ edst,
    int* __restrict__ cursor8, unsigned short* __restrict__ esrc) {
  __shared__ short Asm[128 * 136];   // [row][k] full K=128, pitch 136
  __shared__ short Bsm[128 * 72];    // [col][k] 64-k chunk, pitch 72
  if (blockIdx.x >= NG1) {           // ---- scatter branch (bucketed cursors)
    const int eblk = blockIdx.x - NG1;
    const int e = eblk * 256 + threadIdx.x;
    if (e < E_EDGES) {
      const int pos = atomicAdd(&cursor8[(eblk & 7) * BSTRIDE + edst[e]], 1);
      esrc[pos] = (unsigned short)esrc_in[e];
    }
    return;
  }
  // ---- gemm1 branch
  const int tid = threadIdx.x, lane = tid & 63, wave = tid >> 6;
  const int lm = lane & 15, quad = lane >> 4;
  const int r0 = blockIdx.x * 128;
  const int wrow = (wave & 1) * 64, wcol = (wave >> 1) * 64;
  const int srow = tid >> 1;
  const int scolA = (tid & 1) * 64;
  const int scolB = (tid & 1) * 32;
  const int arow = min(r0 + srow, N_NODES - 1);
#pragma unroll
  for (int i = 0; i < 8; i++) {
    const int col = scolA + i * 8;
    const float4 v0 = *(const float4*)&A[(size_t)arow * 128 + col];
    const float4 v1 = *(const float4*)&A[(size_t)arow * 128 + col + 4];
    ushort4 u0 = { f2bf(v0.x), f2bf(v0.y), f2bf(v0.z), f2bf(v0.w) };
    ushort4 u1 = { f2bf(v1.x), f2bf(v1.y), f2bf(v1.z), f2bf(v1.w) };
    *(ushort4*)&Asm[srow * 136 + col]     = u0;
    *(ushort4*)&Asm[srow * 136 + col + 4] = u1;
  }
  for (int ct = 0; ct < 4; ct++) {
    f32x4 acc[4][4];
#pragma unroll
    for (int mt = 0; mt < 4; mt++)
#pragma unroll
      for (int nt = 0; nt < 4; nt++)
        acc[mt][nt] = (f32x4){0.f, 0.f, 0.f, 0.f};
    for (int kc = 0; kc < 128; kc += 64) {
      __syncthreads();
#pragma unroll
      for (int i = 0; i < 4; i++) {
        const int col = scolB + i * 8;
        *(uint4*)&Bsm[srow * 72 + col] =
            *(const uint4*)&Bt[(size_t)(ct * 128 + srow) * 128 + kc + col];
      }
      __syncthreads();
#pragma unroll
      for (int s = 0; s < 2; s++) {
        s16x8 af[4], bfr[4];
#pragma unroll
        for (int mt = 0; mt < 4; mt++)
          af[mt] = *(const s16x8*)&Asm[(wrow + mt * 16 + lm) * 136 + kc + s * 32 + quad * 8];
#pragma unroll
        for (int nt = 0; nt < 4; nt++)
          bfr[nt] = *(const s16x8*)&Bsm[(wcol + nt * 16 + lm) * 72 + s * 32 + quad * 8];
#pragma unroll
        for (int mt = 0; mt < 4; mt++)
#pragma unroll
          for (int nt = 0; nt < 4; nt++)
            acc[mt][nt] = __builtin_amdgcn_mfma_f32_16x16x32_bf16(af[mt], bfr[nt], acc[mt][nt], 0, 0, 0);
      }
    }
#pragma unroll
    for (int mt = 0; mt < 4; mt++) {
#pragma unroll
      for (int r = 0; r < 4; r++) {
        const int row = r0 + wrow + mt * 16 + quad * 4 + r;
        if (row < N_NODES) {
#pragma unroll
          for (int nt = 0; nt < 4; nt++) {
            const int col = ct * 128 + wcol + nt * 16 + lm;
            Cc[(size_t)row * 512 + col] = f2h(acc[mt][nt][r]);
          }
        }
      }
    }
  }
}

// -------------------------------------- GEMM2: h1[N,256] bf16 -> xlr2[N,128] f16
template<int KTOT>
__global__ __launch_bounds__(256) void gemm_mfma(
    const unsigned short* __restrict__ A, const unsigned short* __restrict__ Bt,
    unsigned short* __restrict__ Cc, int N, int Mtot) {
  __shared__ short Asm[128 * 72];
  __shared__ short Bsm[128 * 72];
  const int tid  = threadIdx.x;
  const int lane = tid & 63;
  const int wave = tid >> 6;
  const int lm   = lane & 15, quad = lane >> 4;
  const int r0   = blockIdx.x * 128;
  const int c0   = blockIdx.y * 128;
  const int wrow = (wave & 1) * 64;
  const int wcol = (wave >> 1) * 64;
  const int srow = tid >> 1;
  const int scol = (tid & 1) * 32;

  f32x4 acc[4][4];
#pragma unroll
  for (int mt = 0; mt < 4; mt++)
#pragma unroll
    for (int nt = 0; nt < 4; nt++)
      acc[mt][nt] = (f32x4){0.f, 0.f, 0.f, 0.f};

  const int arow = min(r0 + srow, N - 1);
  for (int kc = 0; kc < KTOT; kc += 64) {
#pragma unroll
    for (int i = 0; i < 4; i++) {     // A already bf16: raw copy
      const int col = scol + i * 8;
      *(uint4*)&Asm[srow * 72 + col] = *(const uint4*)&A[(size_t)arow * KTOT + kc + col];
    }
#pragma unroll
    for (int i = 0; i < 4; i++) {
      const int col = scol + i * 8;
      *(uint4*)&Bsm[srow * 72 + col] = *(const uint4*)&Bt[(size_t)(c0 + srow) * KTOT + kc + col];
    }
    __syncthreads();
#pragma unroll
    for (int s = 0; s < 2; s++) {
      s16x8 af[4], bfr[4];
#pragma unroll
      for (int mt = 0; mt < 4; mt++)
        af[mt] = *(const s16x8*)&Asm[(wrow + mt * 16 + lm) * 72 + s * 32 + quad * 8];
#pragma unroll
      for (int nt = 0; nt < 4; nt++)
        bfr[nt] = *(const s16x8*)&Bsm[(wcol + nt * 16 + lm) * 72 + s * 32 + quad * 8];
#pragma unroll
      for (int mt = 0; mt < 4; mt++)
#pragma unroll
        for (int nt = 0; nt < 4; nt++)
          acc[mt][nt] = __builtin_amdgcn_mfma_f32_16x16x32_bf16(af[mt], bfr[nt], acc[mt][nt], 0, 0, 0);
    }
    __syncthreads();
  }
#pragma unroll
  for (int mt = 0; mt < 4; mt++) {
#pragma unroll
    for (int r = 0; r < 4; r++) {
      const int row = r0 + wrow + mt * 16 + quad * 4 + r;
      if (row < N) {
#pragma unroll
        for (int nt = 0; nt < 4; nt++) {
          const int col = c0 + wcol + nt * 16 + lm;
          Cc[(size_t)row * Mtot + col] = f2h(acc[mt][nt][r]);
        }
      }
    }
  }
}

// --------------------------------------------- fused gather+softmax+aggregate
// Layer 1: persistent waves; wave per dst; 32 lanes per edge (16B gather),
// halves do even/odd edges, 2 chains per half (proven 36-VGPR shape).
__global__ __launch_bounds__(256) void agg1_kernel(
    const unsigned short* __restrict__ xlr, const float* __restrict__ att,
    const float* __restrict__ bias, const int* __restrict__ offs,
    const unsigned short* __restrict__ esrc, unsigned short* __restrict__ out, int N) {
  const int lane = threadIdx.x & 63;
  const int ln = lane & 31, half = lane >> 5;
  const float4 at0 = *(const float4*)(att + ln * 8);
  const float4 at1 = *(const float4*)(att + ln * 8 + 4);
  const h2 A01 = {(_Float16)(at0.x * LOG2E), (_Float16)(at0.y * LOG2E)};
  const h2 A23 = {(_Float16)(at0.z * LOG2E), (_Float16)(at0.w * LOG2E)};
  const h2 A45 = {(_Float16)(at1.x * LOG2E), (_Float16)(at1.y * LOG2E)};
  const h2 A67 = {(_Float16)(at1.z * LOG2E), (_Float16)(at1.w * LOG2E)};
  const float4 b0 = *(const float4*)(bias + ln * 8);
  const float4 b1v = *(const float4*)(bias + ln * 8 + 4);
  const int wid0 = blockIdx.x * 4 + (threadIdx.x >> 6);

  for (int d = wid0; d < N; d += PWAVES) {
    const uint4 xru = *(const uint4*)(xlr + (size_t)d * 512 + 256 + ln * 8);
    const h2 xr01 = bch2(xru.x), xr23 = bch2(xru.y), xr45 = bch2(xru.z), xr67 = bch2(xru.w);
    const int beg = offs[d], end = offs[d + 1];
    const int len = end - beg;

    float l[2] = {0.f, 0.f};
    float ac[2][8] = {};

#define EDGE1(s, c)                                                           \
  {                                                                           \
    const uint4 xu = *(const uint4*)(xlr + (size_t)(s) * 512 + ln * 8);       \
    const h2 x01 = bch2(xu.x), x23 = bch2(xu.y);                              \
    const h2 x45 = bch2(xu.z), x67 = bch2(xu.w);                              \
    float p = fdot2f(leaky2(x01 + xr01), A01,                                 \
              fdot2f(leaky2(x23 + xr23), A23,                                 \
              fdot2f(leaky2(x45 + xr45), A45,                                 \
              fdot2f(leaky2(x67 + xr67), A67, 0.f))));                        \
    p += __shfl_xor(p, 1);                                                    \
    p += __shfl_xor(p, 2);                                                    \
    p += __shfl_xor(p, 4);                                                    \
    const float w = exp2f(p);                                                 \
    l[c] += w;                                                                \
    ac[c][0] = fmaf(w, (float)x01[0], ac[c][0]);                              \
    ac[c][1] = fmaf(w, (float)x01[1], ac[c][1]);                              \
    ac[c][2] = fmaf(w, (float)x23[0], ac[c][2]);                              \
    ac[c][3] = fmaf(w, (float)x23[1], ac[c][3]);                              \
    ac[c][4] = fmaf(w, (float)x45[0], ac[c][4]);                              \
    ac[c][5] = fmaf(w, (float)x45[1], ac[c][5]);                              \
    ac[c][6] = fmaf(w, (float)x67[0], ac[c][6]);                              \
    ac[c][7] = fmaf(w, (float)x67[1], ac[c][7]);                              \
  }

    if (half == 0) EDGE1(d, 0)  // self loop
    int j = half;
    for (; j + 2 < len; j += 4) {
      const int s0 = esrc[beg + j], s1 = esrc[beg + j + 2];
      EDGE1(s0, 0)
      EDGE1(s1, 1)
    }
    if (j < len) { const int s = esrc[beg + j]; EDGE1(s, 0) j += 2; }
    if (j < len) { const int s = esrc[beg + j]; EDGE1(s, 1) }
#undef EDGE1

    float lt = l[0] + l[1];
    lt += __shfl_xor(lt, 32);
    const float inv = 1.f / (lt + 1e-16f);
    float o[8];
#pragma unroll
    for (int t = 0; t < 8; t++) {
      o[t] = ac[0][t] + ac[1][t];
      o[t] += __shfl_xor(o[t], 32);
    }
    if (half == 0) {
      ushort4 u0, u1;  // h1 in bf16 (feeds gemm2 directly)
      u0.x = f2bf(fmaxf(o[0] * inv + b0.x, 0.f));
      u0.y = f2bf(fmaxf(o[1] * inv + b0.y, 0.f));
      u0.z = f2bf(fmaxf(o[2] * inv + b0.z, 0.f));
      u0.w = f2bf(fmaxf(o[3] * inv + b0.w, 0.f));
      u1.x = f2bf(fmaxf(o[4] * inv + b1v.x, 0.f));
      u1.y = f2bf(fmaxf(o[5] * inv + b1v.y, 0.f));
      u1.z = f2bf(fmaxf(o[6] * inv + b1v.z, 0.f));
      u1.w = f2bf(fmaxf(o[7] * inv + b1v.w, 0.f));
      *(ushort4*)(out + (size_t)d * 256 + ln * 8)     = u0;
      *(ushort4*)(out + (size_t)d * 256 + ln * 8 + 4) = u1;
    }
  }
}

// Layer 2: persistent waves; 8 lanes per edge (16B = full 128B row),
// 8 octs x 2 chains.
__global__ __launch_bounds__(256) void agg2_kernel(
    const unsigned short* __restrict__ xlr, const float* __restrict__ att,
    const float* __restrict__ bias, const int* __restrict__ offs,
    const unsigned short* __restrict__ esrc, float* __restrict__ out, int N) {
  const int lane = threadIdx.x & 63;
  const int ln = lane & 7, oct = lane >> 3;
  const float4 at0 = *(const float4*)(att + ln * 8);
  const float4 at1 = *(const float4*)(att + ln * 8 + 4);
  const h2 A01 = {(_Float16)(at0.x * LOG2E), (_Float16)(at0.y * LOG2E)};
  const h2 A23 = {(_Float16)(at0.z * LOG2E), (_Float16)(at0.w * LOG2E)};
  const h2 A45 = {(_Float16)(at1.x * LOG2E), (_Float16)(at1.y * LOG2E)};
  const h2 A67 = {(_Float16)(at1.z * LOG2E), (_Float16)(at1.w * LOG2E)};
  const float4 b0 = *(const float4*)(bias + ln * 8);
  const float4 b1v = *(const float4*)(bias + ln * 8 + 4);
  const int wid0 = blockIdx.x * 4 + (threadIdx.x >> 6);

  for (int d = wid0; d < N; d += PWAVES) {
    const uint4 xru = *(const uint4*)(xlr + (size_t)d * 128 + 64 + ln * 8);
    const h2 xr01 = bch2(xru.x), xr23 = bch2(xru.y), xr45 = bch2(xru.z), xr67 = bch2(xru.w);
    const int beg = offs[d], end = offs[d + 1];
    const int len = end - beg;

    float l[2] = {0.f, 0.f};
    float ac[2][8] = {};

#define EDGE2(s, c)                                                           \
  {                                                                           \
    const uint4 xu = *(const uint4*)(xlr + (size_t)(s) * 128 + ln * 8);       \
    const h2 x01 = bch2(xu.x), x23 = bch2(xu.y);                              \
    const h2 x45 = bch2(xu.z), x67 = bch2(xu.w);                              \
    float p = fdot2f(leaky2(x01 + xr01), A01,                                 \
              fdot2f(leaky2(x23 + xr23), A23,                                 \
              fdot2f(leaky2(x45 + xr45), A45,                                 \
              fdot2f(leaky2(x67 + xr67), A67, 0.f))));                        \
    p += __shfl_xor(p, 1);                                                    \
    p += __shfl_xor(p, 2);                                                    \
    p += __shfl_xor(p, 4);                                                    \
    const float w = exp2f(p);                                                 \
    l[c] += w;                                                                \
    ac[c][0] = fmaf(w, (float)x01[0], ac[c][0]);                              \
    ac[c][1] = fmaf(w, (float)x01[1], ac[c][1]);                              \
    ac[c][2] = fmaf(w, (float)x23[0], ac[c][2]);                              \
    ac[c][3] = fmaf(w, (float)x23[1], ac[c][3]);                              \
    ac[c][4] = fmaf(w, (float)x45[0], ac[c][4]);                              \
    ac[c][5] = fmaf(w, (float)x45[1], ac[c][5]);                              \
    ac[c][6] = fmaf(w, (float)x67[0], ac[c][6]);                              \
    ac[c][7] = fmaf(w, (float)x67[1], ac[c][7]);                              \
  }

    if (oct == 0) EDGE2(d, 0)  // self loop
    int j = oct;
    for (; j + 8 < len; j += 16) {
      const int s0 = esrc[beg + j], s1 = esrc[beg + j + 8];
      EDGE2(s0, 0)
      EDGE2(s1, 1)
    }
    if (j < len) { const int s = esrc[beg + j]; EDGE2(s, 0) j += 8; }
    if (j < len) { const int s = esrc[beg + j]; EDGE2(s, 1) }
#undef EDGE2

    float lt = l[0] + l[1];
    lt += __shfl_xor(lt, 8);
    lt += __shfl_xor(lt, 16);
    lt += __shfl_xor(lt, 32);
    const float inv = 1.f / (lt + 1e-16f);
    float o[8];
#pragma unroll
    for (int t = 0; t < 8; t++) {
      o[t] = ac[0][t] + ac[1][t];
      o[t] += __shfl_xor(o[t], 8);
      o[t] += __shfl_xor(o[t], 16);
      o[t] += __shfl_xor(o[t], 32);
    }
    if (oct == 0) {
      float4 v0, v1;
      v0.x = o[0] * inv + b0.x;  v0.y = o[1] * inv + b0.y;
      v0.z = o[2] * inv + b0.z;  v0.w = o[3] * inv + b0.w;
      v1.x = o[4] * inv + b1v.x; v1.y = o[5] * inv + b1v.y;
      v1.z = o[6] * inv + b1v.z; v1.w = o[7] * inv + b1v.w;
      *(float4*)(out + (size_t)d * 64 + ln * 8)     = v0;
      *(float4*)(out + (size_t)d * 64 + ln * 8 + 4) = v1;
    }
  }
}

// ------------------------------------------------------------------- pooling
__global__ __launch_bounds__(256) void pool_kernel(
    const float* __restrict__ h, const int* __restrict__ batch, int N,
    float* __restrict__ pooled, float* __restrict__ cnt) {
  const int wid  = (blockIdx.x * blockDim.x + threadIdx.x) >> 6;
  const int lane = threadIdx.x & 63;
  const int nw   = (gridDim.x * blockDim.x) >> 6;
  const int per  = (N + nw - 1) / nw;
  const int beg  = wid * per;
  if (beg >= N) return;
  const int end = min(beg + per, N);
  int g = batch[beg];
  float acc = 0.f, c = 0.f;
  for (int d = beg; d < end; d++) {
    const int gd = batch[d];
    if (gd != g) {
      atomicAdd(&pooled[g * C2 + lane], acc);
      if (lane == 0) atomicAdd(&cnt[g], c);
      acc = 0.f; c = 0.f; g = gd;
    }
    acc += h[(size_t)d * C2 + lane];
    c += 1.f;
  }
  atomicAdd(&pooled[g * C2 + lane], acc);
  if (lane == 0) atomicAdd(&cnt[g], c);
}

__global__ void final_kernel(const float* __restrict__ pooled, const float* __restrict__ cnt,
                             const float* __restrict__ Wo, const float* __restrict__ bo,
                             float* __restrict__ out) {
  const int lane = threadIdx.x;  // 64 threads
  for (int g = 0; g < NGRAPH; g++) {
    float p = (pooled[g * C2 + lane] / fmaxf(cnt[g], 1.f)) * Wo[lane];
    p += __shfl_xor(p, 1);
    p += __shfl_xor(p, 2);
    p += __shfl_xor(p, 4);
    p += __shfl_xor(p, 8);
    p += __shfl_xor(p, 16);
    p += __shfl_xor(p, 32);
    if (lane == 0) out[g] = p + bo[0];
  }
}

// ---------------------------------------------------------------------------
extern "C" void kernel_launch(void* const* d_in, const int* in_sizes, int n_in,
                              void* d_out, int out_size, void* d_ws, size_t ws_size,
                              hipStream_t stream) {
  const float* x    = (const float*)d_in[0];
  const int*   edge = (const int*)d_in[1];
  const int*   batch= (const int*)d_in[2];
  const float* Wl1  = (const float*)d_in[3];
  const float* Wr1  = (const float*)d_in[4];
  const float* att1 = (const float*)d_in[5];
  const float* b1   = (const float*)d_in[6];
  const float* Wl2  = (const float*)d_in[7];
  const float* Wr2  = (const float*)d_in[8];
  const float* att2 = (const float*)d_in[9];
  const float* b2   = (const float*)d_in[10];
  const float* Wo   = (const float*)d_in[11];
  const float* bo   = (const float*)d_in[12];
  float* out = (float*)d_out;

  char* p = (char*)d_ws;
  unsigned short* xlr1 = (unsigned short*)(p);               // 51,200,000 (f16)
  unsigned short* h1   = (unsigned short*)(p + 51200000);    // 25,600,000 (bf16)
  unsigned short* xlr2 = (unsigned short*)(p + 76800000);    // 12,800,000 (f16)
  float*          out2 = (float*)(p + 89600000);             // 12,800,000 (f32)
  unsigned short* Bt1  = (unsigned short*)(p + 102400000);   // 131,072
  unsigned short* Bt2  = (unsigned short*)(p + 102531072);   // 65,536
  char* aux = p + 102596608;
  int*   deg8    = (int*)aux;                                // 8*50176*4 = 1,605,632
  float* pooled  = (float*)(aux + 1605632);                  // 2,048
  float* cnt     = (float*)(aux + 1607680);                  // 32
  int*   offs    = (int*)(aux + 1607712);                    // 200,064
  int*   cursor8 = (int*)(aux + 1807776);                    // 1,605,632
  unsigned short* esrc = (unsigned short*)(aux + 3413408);   // 1,600,000
  int*   incl    = (int*)(aux + 5013408);                    // 200,704
  int*   bsum    = (int*)(aux + 5214112);                    // 256

  const int* edst = edge + E_EDGES;

  // one memset covers deg8 + pooled + cnt (adjacent)
  hipMemsetAsync(deg8, 0, 1607712, stream);

  // transpose+cast weights || bucketed degree histogram
  prep_kernel<<<384 + NSCAT, 256, 0, stream>>>(Wl1, Wr1, Wl2, Wr2, Bt1, Bt2, edst, deg8);

  const int nb = (N_NODES + 1023) / 1024;  // 49
  scan1<<<nb, 1024, 0, stream>>>(deg8, N_NODES, incl, bsum);
  scan3<<<(N_NODES + 255) / 256, 256, 0, stream>>>(deg8, incl, bsum, nb, N_NODES, offs, cursor8);

  // gemm1 (x @ [Wl1|Wr1] -> f16) || bucketed scatter into CSR
  gemm1_scatter<<<NG1 + NSCAT, 256, 0, stream>>>(x, Bt1, xlr1, edge, edst, cursor8, esrc);

  agg1_kernel<<<PWAVES / 4, 256, 0, stream>>>(xlr1, att1, b1, offs, esrc, h1, N_NODES);

  gemm_mfma<HC1><<<dim3((N_NODES + 127) / 128, 1), 256, 0, stream>>>(h1, Bt2, xlr2, N_NODES, 128);

  agg2_kernel<<<PWAVES / 4, 256, 0, stream>>>(xlr2, att2, b2, offs, esrc, out2, N_NODES);

  pool_kernel<<<196, 256, 0, stream>>>(out2, batch, N_NODES, pooled, cnt);
  final_kernel<<<1, 64, 0, stream>>>(pooled, cnt, Wo, bo, out);
}

// Round 10
// 335.379 us; speedup vs baseline: 1.0494x; 1.0494x over previous
//
#include <hip/hip_runtime.h>
#include <math.h>

#define N_NODES 50000
#define E_EDGES 800000
#define FIN     128
#define HC1     256   // H*C = 4*64
#define C2      64
#define NGRAPH  8
#define LOG2E   1.4426950408889634f
#define NG1     391   // gemm1 blocks
#define NCNT    1563  // count/scatter blocks: E/(256*2)

typedef short  s16x8 __attribute__((ext_vector_type(8)));
typedef float  f32x4 __attribute__((ext_vector_type(4)));
typedef _Float16 h2  __attribute__((ext_vector_type(2)));

__device__ __forceinline__ unsigned short f2bf(float f) {
  union { float f; unsigned u; } v; v.f = f;
  unsigned r = v.u + 0x7FFFu + ((v.u >> 16) & 1u);  // RNE
  return (unsigned short)(r >> 16);
}
__device__ __forceinline__ h2 bch2(unsigned u) { return __builtin_bit_cast(h2, u); }
__device__ __forceinline__ unsigned short f2h(float f) {
  _Float16 h = (_Float16)f;
  return __builtin_bit_cast(unsigned short, h);
}
__device__ __forceinline__ float h2f(unsigned short u) {
  return (float)__builtin_bit_cast(_Float16, u);
}

__device__ __forceinline__ float fdot2f(h2 a, h2 b, float c) {
#if __has_builtin(__builtin_amdgcn_fdot2)
  return __builtin_amdgcn_fdot2(a, b, c, false);
#else
  return c + (float)a[0] * (float)b[0] + (float)a[1] * (float)b[1];
#endif
}

// leaky_relu in packed f16: max(e, 0.2*e) exact for both signs.
__device__ __forceinline__ h2 leaky2(h2 e) {
  const h2 c02 = {(_Float16)0.2f, (_Float16)0.2f};
  return __builtin_elementwise_max(e, e * c02);
}

// ---------------------- prep: weight transpose+cast  ||  degree histogram
__global__ __launch_bounds__(256) void prep_kernel(
    const float* __restrict__ Wl1, const float* __restrict__ Wr1,
    const float* __restrict__ Wl2, const float* __restrict__ Wr2,
    unsigned short* __restrict__ Bt1, unsigned short* __restrict__ Bt2,
    const int* __restrict__ edst, int* __restrict__ deg) {
  const int b = blockIdx.x;
  if (b < 384) {
    const int idx = b * 256 + threadIdx.x;
    if (idx < 512 * 128) {            // Bt1 [512][128] from [128][256] pair
      const int n = idx >> 7, k = idx & 127;
      const float* B = (n < 256) ? Wl1 : Wr1;
      const int nn = (n < 256) ? n : n - 256;
      Bt1[idx] = f2bf(B[k * 256 + nn]);
    } else {                          // Bt2 [128][256] from [256][64] pair
      const int t = idx - 512 * 128;
      const int n = t >> 8, k = t & 255;
      const float* B = (n < 64) ? Wl2 : Wr2;
      const int nn = (n < 64) ? n : n - 64;
      Bt2[t] = f2bf(B[k * 64 + nn]);
    }
  } else {
    const int e = (((b - 384) * 256) + threadIdx.x) * 2;
    if (e < E_EDGES) {
      const int2 d2 = *(const int2*)&edst[e];
      atomicAdd(&deg[d2.x], 1);
      atomicAdd(&deg[d2.y], 1);
    }
  }
}

// ------------------------------------------------------------- CSR scan
__global__ __launch_bounds__(1024) void scan1(const int* __restrict__ deg, int N,
                                              int* __restrict__ incl, int* __restrict__ bsum) {
  __shared__ int sd[1024];
  const int tid = threadIdx.x;
  const int i = blockIdx.x * 1024 + tid;
  sd[tid] = (i < N) ? deg[i] : 0;
  __syncthreads();
  for (int off = 1; off < 1024; off <<= 1) {
    int t = 0;
    if (tid >= off) t = sd[tid - off];
    __syncthreads();
    if (tid >= off) sd[tid] += t;
    __syncthreads();
  }
  incl[i] = sd[tid];
  if (tid == 1023) bsum[blockIdx.x] = sd[1023];
}

// apply: per-block redundant exclusive scan of bsum (nb<=64) via wave 0
__global__ __launch_bounds__(256) void scan3(
    const int* __restrict__ deg, const int* __restrict__ incl,
    const int* __restrict__ bsum, int nb, int N,
    int* __restrict__ offs, int* __restrict__ cursor) {
  __shared__ int pb[64];
  if (threadIdx.x < 64) {
    const int lane = threadIdx.x;
    const int orig = (lane < nb) ? bsum[lane] : 0;
    int v = orig;
    for (int off = 1; off < 64; off <<= 1) {
      int t = __shfl_up(v, off);
      if (lane >= off) v += t;
    }
    pb[lane] = v - orig;  // exclusive
  }
  __syncthreads();
  const int i = blockIdx.x * 256 + threadIdx.x;
  if (i >= N) return;
  const int val = incl[i] + pb[i >> 10];
  offs[i + 1] = val;
  cursor[i] = val - deg[i];
  if (i == 0) offs[0] = 0;
}

// --------------------- fused: GEMM1 (x[N,128]->xlr1[N,512])  ||  edge scatter
__global__ __launch_bounds__(256) void gemm1_scatter(
    const float* __restrict__ A, const unsigned short* __restrict__ Bt,
    unsigned short* __restrict__ Cc,
    const int* __restrict__ esrc_in, const int* __restrict__ edst,
    int* __restrict__ cursor, unsigned short* __restrict__ esrc) {
  __shared__ short Asm[128 * 136];   // [row][k] full K=128, pitch 136
  __shared__ short Bsm[128 * 72];    // [col][k] 64-k chunk, pitch 72
  if (blockIdx.x >= NG1) {           // ---- scatter branch
    const int e = (((blockIdx.x - NG1) * 256) + threadIdx.x) * 2;
    if (e < E_EDGES) {
      const int2 s2 = *(const int2*)&esrc_in[e];
      const int2 d2 = *(const int2*)&edst[e];
      const int p0 = atomicAdd(&cursor[d2.x], 1);
      esrc[p0] = (unsigned short)s2.x;
      const int p1 = atomicAdd(&cursor[d2.y], 1);
      esrc[p1] = (unsigned short)s2.y;
    }
    return;
  }
  // ---- gemm1 branch
  const int tid = threadIdx.x, lane = tid & 63, wave = tid >> 6;
  const int lm = lane & 15, quad = lane >> 4;
  const int r0 = blockIdx.x * 128;
  const int wrow = (wave & 1) * 64, wcol = (wave >> 1) * 64;
  const int srow = tid >> 1;
  const int scolA = (tid & 1) * 64;
  const int scolB = (tid & 1) * 32;
  const int arow = min(r0 + srow, N_NODES - 1);
#pragma unroll
  for (int i = 0; i < 8; i++) {
    const int col = scolA + i * 8;
    const float4 v0 = *(const float4*)&A[(size_t)arow * 128 + col];
    const float4 v1 = *(const float4*)&A[(size_t)arow * 128 + col + 4];
    ushort4 u0 = { f2bf(v0.x), f2bf(v0.y), f2bf(v0.z), f2bf(v0.w) };
    ushort4 u1 = { f2bf(v1.x), f2bf(v1.y), f2bf(v1.z), f2bf(v1.w) };
    *(ushort4*)&Asm[srow * 136 + col]     = u0;
    *(ushort4*)&Asm[srow * 136 + col + 4] = u1;
  }
  for (int ct = 0; ct < 4; ct++) {
    f32x4 acc[4][4];
#pragma unroll
    for (int mt = 0; mt < 4; mt++)
#pragma unroll
      for (int nt = 0; nt < 4; nt++)
        acc[mt][nt] = (f32x4){0.f, 0.f, 0.f, 0.f};
    for (int kc = 0; kc < 128; kc += 64) {
      __syncthreads();
#pragma unroll
      for (int i = 0; i < 4; i++) {
        const int col = scolB + i * 8;
        *(uint4*)&Bsm[srow * 72 + col] =
            *(const uint4*)&Bt[(size_t)(ct * 128 + srow) * 128 + kc + col];
      }
      __syncthreads();
#pragma unroll
      for (int s = 0; s < 2; s++) {
        s16x8 af[4], bfr[4];
#pragma unroll
        for (int mt = 0; mt < 4; mt++)
          af[mt] = *(const s16x8*)&Asm[(wrow + mt * 16 + lm) * 136 + kc + s * 32 + quad * 8];
#pragma unroll
        for (int nt = 0; nt < 4; nt++)
          bfr[nt] = *(const s16x8*)&Bsm[(wcol + nt * 16 + lm) * 72 + s * 32 + quad * 8];
#pragma unroll
        for (int mt = 0; mt < 4; mt++)
#pragma unroll
          for (int nt = 0; nt < 4; nt++)
            acc[mt][nt] = __builtin_amdgcn_mfma_f32_16x16x32_bf16(af[mt], bfr[nt], acc[mt][nt], 0, 0, 0);
      }
    }
#pragma unroll
    for (int mt = 0; mt < 4; mt++) {
#pragma unroll
      for (int r = 0; r < 4; r++) {
        const int row = r0 + wrow + mt * 16 + quad * 4 + r;
        if (row < N_NODES) {
#pragma unroll
          for (int nt = 0; nt < 4; nt++) {
            const int col = ct * 128 + wcol + nt * 16 + lm;
            Cc[(size_t)row * 512 + col] = f2h(acc[mt][nt][r]);
          }
        }
      }
    }
  }
}

// -------------------------------------- GEMM2: h1[N,256] bf16 -> xlr2[N,128] f16
template<int KTOT>
__global__ __launch_bounds__(256) void gemm_mfma(
    const unsigned short* __restrict__ A, const unsigned short* __restrict__ Bt,
    unsigned short* __restrict__ Cc, int N, int Mtot) {
  __shared__ short Asm[128 * 72];
  __shared__ short Bsm[128 * 72];
  const int tid  = threadIdx.x;
  const int lane = tid & 63;
  const int wave = tid >> 6;
  const int lm   = lane & 15, quad = lane >> 4;
  const int r0   = blockIdx.x * 128;
  const int c0   = blockIdx.y * 128;
  const int wrow = (wave & 1) * 64;
  const int wcol = (wave >> 1) * 64;
  const int srow = tid >> 1;
  const int scol = (tid & 1) * 32;

  f32x4 acc[4][4];
#pragma unroll
  for (int mt = 0; mt < 4; mt++)
#pragma unroll
    for (int nt = 0; nt < 4; nt++)
      acc[mt][nt] = (f32x4){0.f, 0.f, 0.f, 0.f};

  const int arow = min(r0 + srow, N - 1);
  for (int kc = 0; kc < KTOT; kc += 64) {
#pragma unroll
    for (int i = 0; i < 4; i++) {     // A already bf16: raw copy
      const int col = scol + i * 8;
      *(uint4*)&Asm[srow * 72 + col] = *(const uint4*)&A[(size_t)arow * KTOT + kc + col];
    }
#pragma unroll
    for (int i = 0; i < 4; i++) {
      const int col = scol + i * 8;
      *(uint4*)&Bsm[srow * 72 + col] = *(const uint4*)&Bt[(size_t)(c0 + srow) * KTOT + kc + col];
    }
    __syncthreads();
#pragma unroll
    for (int s = 0; s < 2; s++) {
      s16x8 af[4], bfr[4];
#pragma unroll
      for (int mt = 0; mt < 4; mt++)
        af[mt] = *(const s16x8*)&Asm[(wrow + mt * 16 + lm) * 72 + s * 32 + quad * 8];
#pragma unroll
      for (int nt = 0; nt < 4; nt++)
        bfr[nt] = *(const s16x8*)&Bsm[(wcol + nt * 16 + lm) * 72 + s * 32 + quad * 8];
#pragma unroll
      for (int mt = 0; mt < 4; mt++)
#pragma unroll
        for (int nt = 0; nt < 4; nt++)
          acc[mt][nt] = __builtin_amdgcn_mfma_f32_16x16x32_bf16(af[mt], bfr[nt], acc[mt][nt], 0, 0, 0);
    }
    __syncthreads();
  }
#pragma unroll
  for (int mt = 0; mt < 4; mt++) {
#pragma unroll
    for (int r = 0; r < 4; r++) {
      const int row = r0 + wrow + mt * 16 + quad * 4 + r;
      if (row < N) {
#pragma unroll
        for (int nt = 0; nt < 4; nt++) {
          const int col = c0 + wcol + nt * 16 + lm;
          Cc[(size_t)row * Mtot + col] = f2h(acc[mt][nt][r]);
        }
      }
    }
  }
}

// --------------------------------------------- fused gather+softmax+aggregate
// Layer 1 (round-8 proven shape): wave per dst; 32 lanes per edge (lane owns
// 8 ch = 16B gather), halves do even/odd edges, 2 chains per half.
__global__ __launch_bounds__(256) void agg1_kernel(
    const unsigned short* __restrict__ xlr, const float* __restrict__ att,
    const float* __restrict__ bias, const int* __restrict__ offs,
    const unsigned short* __restrict__ esrc, unsigned short* __restrict__ out, int N) {
  const int lane = threadIdx.x & 63;
  const int ln = lane & 31, half = lane >> 5;
  const int d = blockIdx.x * 4 + (threadIdx.x >> 6);
  if (d >= N) return;
  const uint4 xru = *(const uint4*)(xlr + (size_t)d * 512 + 256 + ln * 8);
  const h2 xr01 = bch2(xru.x), xr23 = bch2(xru.y), xr45 = bch2(xru.z), xr67 = bch2(xru.w);
  const float4 at0 = *(const float4*)(att + ln * 8);
  const float4 at1 = *(const float4*)(att + ln * 8 + 4);
  const h2 A01 = {(_Float16)(at0.x * LOG2E), (_Float16)(at0.y * LOG2E)};
  const h2 A23 = {(_Float16)(at0.z * LOG2E), (_Float16)(at0.w * LOG2E)};
  const h2 A45 = {(_Float16)(at1.x * LOG2E), (_Float16)(at1.y * LOG2E)};
  const h2 A67 = {(_Float16)(at1.z * LOG2E), (_Float16)(at1.w * LOG2E)};
  const int beg = offs[d], end = offs[d + 1];
  const int len = end - beg;

  float l[2] = {0.f, 0.f};
  float ac[2][8] = {};

#define EDGE1(s, c)                                                           \
  {                                                                           \
    const uint4 xu = *(const uint4*)(xlr + (size_t)(s) * 512 + ln * 8);       \
    const h2 x01 = bch2(xu.x), x23 = bch2(xu.y);                              \
    const h2 x45 = bch2(xu.z), x67 = bch2(xu.w);                              \
    float p = fdot2f(leaky2(x01 + xr01), A01,                                 \
              fdot2f(leaky2(x23 + xr23), A23,                                 \
              fdot2f(leaky2(x45 + xr45), A45,                                 \
              fdot2f(leaky2(x67 + xr67), A67, 0.f))));                        \
    p += __shfl_xor(p, 1);                                                    \
    p += __shfl_xor(p, 2);                                                    \
    p += __shfl_xor(p, 4);                                                    \
    const float w = exp2f(p);                                                 \
    l[c] += w;                                                                \
    ac[c][0] = fmaf(w, (float)x01[0], ac[c][0]);                              \
    ac[c][1] = fmaf(w, (float)x01[1], ac[c][1]);                              \
    ac[c][2] = fmaf(w, (float)x23[0], ac[c][2]);                              \
    ac[c][3] = fmaf(w, (float)x23[1], ac[c][3]);                              \
    ac[c][4] = fmaf(w, (float)x45[0], ac[c][4]);                              \
    ac[c][5] = fmaf(w, (float)x45[1], ac[c][5]);                              \
    ac[c][6] = fmaf(w, (float)x67[0], ac[c][6]);                              \
    ac[c][7] = fmaf(w, (float)x67[1], ac[c][7]);                              \
  }

  if (half == 0) EDGE1(d, 0)  // self loop
  int j = half;
  for (; j + 2 < len; j += 4) {
    const int s0 = esrc[beg + j], s1 = esrc[beg + j + 2];
    EDGE1(s0, 0)
    EDGE1(s1, 1)
  }
  if (j < len) { const int s = esrc[beg + j]; EDGE1(s, 0) j += 2; }
  if (j < len) { const int s = esrc[beg + j]; EDGE1(s, 1) }
#undef EDGE1

  float lt = l[0] + l[1];
  lt += __shfl_xor(lt, 32);
  const float inv = 1.f / (lt + 1e-16f);
  float o[8];
#pragma unroll
  for (int t = 0; t < 8; t++) {
    o[t] = ac[0][t] + ac[1][t];
    o[t] += __shfl_xor(o[t], 32);
  }
  if (half == 0) {
    const float4 b0 = *(const float4*)(bias + ln * 8);
    const float4 b1v = *(const float4*)(bias + ln * 8 + 4);
    ushort4 u0, u1;  // h1 in bf16 (feeds gemm2 directly)
    u0.x = f2bf(fmaxf(o[0] * inv + b0.x, 0.f));
    u0.y = f2bf(fmaxf(o[1] * inv + b0.y, 0.f));
    u0.z = f2bf(fmaxf(o[2] * inv + b0.z, 0.f));
    u0.w = f2bf(fmaxf(o[3] * inv + b0.w, 0.f));
    u1.x = f2bf(fmaxf(o[4] * inv + b1v.x, 0.f));
    u1.y = f2bf(fmaxf(o[5] * inv + b1v.y, 0.f));
    u1.z = f2bf(fmaxf(o[6] * inv + b1v.z, 0.f));
    u1.w = f2bf(fmaxf(o[7] * inv + b1v.w, 0.f));
    *(ushort4*)(out + (size_t)d * 256 + ln * 8)     = u0;
    *(ushort4*)(out + (size_t)d * 256 + ln * 8 + 4) = u1;
  }
}

// Layer 2 (round-8 shape): wave per dst; 8 lanes per edge (16B = full 128B
// row), 8 octs x 2 chains. Writes out2 (f16).
__global__ __launch_bounds__(256) void agg2_kernel(
    const unsigned short* __restrict__ xlr, const float* __restrict__ att,
    const float* __restrict__ bias, const int* __restrict__ offs,
    const unsigned short* __restrict__ esrc, unsigned short* __restrict__ out, int N) {
  const int lane = threadIdx.x & 63;
  const int ln = lane & 7, oct = lane >> 3;
  const int d = blockIdx.x * 4 + (threadIdx.x >> 6);
  if (d >= N) return;
  const uint4 xru = *(const uint4*)(xlr + (size_t)d * 128 + 64 + ln * 8);
  const h2 xr01 = bch2(xru.x), xr23 = bch2(xru.y), xr45 = bch2(xru.z), xr67 = bch2(xru.w);
  const float4 at0 = *(const float4*)(att + ln * 8);
  const float4 at1 = *(const float4*)(att + ln * 8 + 4);
  const h2 A01 = {(_Float16)(at0.x * LOG2E), (_Float16)(at0.y * LOG2E)};
  const h2 A23 = {(_Float16)(at0.z * LOG2E), (_Float16)(at0.w * LOG2E)};
  const h2 A45 = {(_Float16)(at1.x * LOG2E), (_Float16)(at1.y * LOG2E)};
  const h2 A67 = {(_Float16)(at1.z * LOG2E), (_Float16)(at1.w * LOG2E)};
  const int beg = offs[d], end = offs[d + 1];
  const int len = end - beg;

  float l[2] = {0.f, 0.f};
  float ac[2][8] = {};

#define EDGE2(s, c)                                                           \
  {                                                                           \
    const uint4 xu = *(const uint4*)(xlr + (size_t)(s) * 128 + ln * 8);       \
    const h2 x01 = bch2(xu.x), x23 = bch2(xu.y);                              \
    const h2 x45 = bch2(xu.z), x67 = bch2(xu.w);                              \
    float p = fdot2f(leaky2(x01 + xr01), A01,                                 \
              fdot2f(leaky2(x23 + xr23), A23,                                 \
              fdot2f(leaky2(x45 + xr45), A45,                                 \
              fdot2f(leaky2(x67 + xr67), A67, 0.f))));                        \
    p += __shfl_xor(p, 1);                                                    \
    p += __shfl_xor(p, 2);                                                    \
    p += __shfl_xor(p, 4);                                                    \
    const float w = exp2f(p);                                                 \
    l[c] += w;                                                                \
    ac[c][0] = fmaf(w, (float)x01[0], ac[c][0]);                              \
    ac[c][1] = fmaf(w, (float)x01[1], ac[c][1]);                              \
    ac[c][2] = fmaf(w, (float)x23[0], ac[c][2]);                              \
    ac[c][3] = fmaf(w, (float)x23[1], ac[c][3]);                              \
    ac[c][4] = fmaf(w, (float)x45[0], ac[c][4]);                              \
    ac[c][5] = fmaf(w, (float)x45[1], ac[c][5]);                              \
    ac[c][6] = fmaf(w, (float)x67[0], ac[c][6]);                              \
    ac[c][7] = fmaf(w, (float)x67[1], ac[c][7]);                              \
  }

  if (oct == 0) EDGE2(d, 0)  // self loop
  int j = oct;
  for (; j + 8 < len; j += 16) {
    const int s0 = esrc[beg + j], s1 = esrc[beg + j + 8];
    EDGE2(s0, 0)
    EDGE2(s1, 1)
  }
  if (j < len) { const int s = esrc[beg + j]; EDGE2(s, 0) j += 8; }
  if (j < len) { const int s = esrc[beg + j]; EDGE2(s, 1) }
#undef EDGE2

  float lt = l[0] + l[1];
  lt += __shfl_xor(lt, 8);
  lt += __shfl_xor(lt, 16);
  lt += __shfl_xor(lt, 32);
  const float inv = 1.f / (lt + 1e-16f);
  float o[8];
#pragma unroll
  for (int t = 0; t < 8; t++) {
    o[t] = ac[0][t] + ac[1][t];
    o[t] += __shfl_xor(o[t], 8);
    o[t] += __shfl_xor(o[t], 16);
    o[t] += __shfl_xor(o[t], 32);
  }
  if (oct == 0) {
    const float4 b0 = *(const float4*)(bias + ln * 8);
    const float4 b1v = *(const float4*)(bias + ln * 8 + 4);
    ushort4 u0, u1;
    u0.x = f2h(o[0] * inv + b0.x);  u0.y = f2h(o[1] * inv + b0.y);
    u0.z = f2h(o[2] * inv + b0.z);  u0.w = f2h(o[3] * inv + b0.w);
    u1.x = f2h(o[4] * inv + b1v.x); u1.y = f2h(o[5] * inv + b1v.y);
    u1.z = f2h(o[6] * inv + b1v.z); u1.w = f2h(o[7] * inv + b1v.w);
    *(ushort4*)(out + (size_t)d * 64 + ln * 8)     = u0;
    *(ushort4*)(out + (size_t)d * 64 + ln * 8 + 4) = u1;
  }
}

// ------------------------------------------------------------------- pooling
// 196 blocks; wave owns contiguous node range; f16 input, f32 accumulate.
__global__ __launch_bounds__(256) void pool_kernel(
    const unsigned short* __restrict__ h, const int* __restrict__ batch, int N,
    float* __restrict__ pooled, float* __restrict__ cnt) {
  const int wid  = (blockIdx.x * blockDim.x + threadIdx.x) >> 6;
  const int lane = threadIdx.x & 63;
  const int nw   = (gridDim.x * blockDim.x) >> 6;
  const int per  = (N + nw - 1) / nw;
  const int beg  = wid * per;
  if (beg >= N) return;
  const int end = min(beg + per, N);
  int g = batch[beg];
  float acc = 0.f, c = 0.f;
  for (int d = beg; d < end; d++) {
    const int gd = batch[d];
    if (gd != g) {
      atomicAdd(&pooled[g * C2 + lane], acc);
      if (lane == 0) atomicAdd(&cnt[g], c);
      acc = 0.f; c = 0.f; g = gd;
    }
    acc += h2f(h[(size_t)d * C2 + lane]);
    c += 1.f;
  }
  atomicAdd(&pooled[g * C2 + lane], acc);
  if (lane == 0) atomicAdd(&cnt[g], c);
}

__global__ void final_kernel(const float* __restrict__ pooled, const float* __restrict__ cnt,
                             const float* __restrict__ Wo, const float* __restrict__ bo,
                             float* __restrict__ out) {
  const int lane = threadIdx.x;  // 64 threads
  for (int g = 0; g < NGRAPH; g++) {
    float p = (pooled[g * C2 + lane] / fmaxf(cnt[g], 1.f)) * Wo[lane];
    p += __shfl_xor(p, 1);
    p += __shfl_xor(p, 2);
    p += __shfl_xor(p, 4);
    p += __shfl_xor(p, 8);
    p += __shfl_xor(p, 16);
    p += __shfl_xor(p, 32);
    if (lane == 0) out[g] = p + bo[0];
  }
}

// ---------------------------------------------------------------------------
extern "C" void kernel_launch(void* const* d_in, const int* in_sizes, int n_in,
                              void* d_out, int out_size, void* d_ws, size_t ws_size,
                              hipStream_t stream) {
  const float* x    = (const float*)d_in[0];
  const int*   edge = (const int*)d_in[1];
  const int*   batch= (const int*)d_in[2];
  const float* Wl1  = (const float*)d_in[3];
  const float* Wr1  = (const float*)d_in[4];
  const float* att1 = (const float*)d_in[5];
  const float* b1   = (const float*)d_in[6];
  const float* Wl2  = (const float*)d_in[7];
  const float* Wr2  = (const float*)d_in[8];
  const float* att2 = (const float*)d_in[9];
  const float* b2   = (const float*)d_in[10];
  const float* Wo   = (const float*)d_in[11];
  const float* bo   = (const float*)d_in[12];
  float* out = (float*)d_out;

  char* p = (char*)d_ws;
  unsigned short* xlr1 = (unsigned short*)(p);               // 51,200,000 (f16)
  unsigned short* h1   = (unsigned short*)(p + 51200000);    // 25,600,000 (bf16)
  unsigned short* xlr2 = (unsigned short*)(p + 76800000);    // 12,800,000 (f16)
  unsigned short* out2 = (unsigned short*)(p + 89600000);    //  6,400,000 (f16)
  unsigned short* Bt1  = (unsigned short*)(p + 96000000);    // 131,072
  unsigned short* Bt2  = (unsigned short*)(p + 96131072);    // 65,536
  char* aux = p + 96196608;
  int*   deg    = (int*)aux;                                 // 200,000
  float* pooled = (float*)(aux + 200000);                    // 2,048
  float* cnt    = (float*)(aux + 202048);                    // 32
  int*   offs   = (int*)(aux + 202080);                      // 200,064
  int*   cursor = (int*)(aux + 402144);                      // 200,000
  unsigned short* esrc = (unsigned short*)(aux + 602144);    // 1,600,000
  int*   incl   = (int*)(aux + 2202144);                     // 200,704
  int*   bsum   = (int*)(aux + 2402848);                     // 256

  const int* edst = edge + E_EDGES;

  // one memset covers deg + pooled + cnt (adjacent)
  hipMemsetAsync(deg, 0, 202080, stream);

  // transpose+cast weights || degree histogram (2 edges/thread)
  prep_kernel<<<384 + NCNT, 256, 0, stream>>>(Wl1, Wr1, Wl2, Wr2, Bt1, Bt2, edst, deg);

  const int nb = (N_NODES + 1023) / 1024;  // 49
  scan1<<<nb, 1024, 0, stream>>>(deg, N_NODES, incl, bsum);
  scan3<<<(N_NODES + 255) / 256, 256, 0, stream>>>(deg, incl, bsum, nb, N_NODES, offs, cursor);

  // gemm1 (x @ [Wl1|Wr1] -> f16) || scatter edges into CSR (2 edges/thread)
  gemm1_scatter<<<NG1 + NCNT, 256, 0, stream>>>(x, Bt1, xlr1, edge, edst, cursor, esrc);

  agg1_kernel<<<(N_NODES + 3) / 4, 256, 0, stream>>>(xlr1, att1, b1, offs, esrc, h1, N_NODES);

  gemm_mfma<HC1><<<dim3((N_NODES + 127) / 128, 1), 256, 0, stream>>>(h1, Bt2, xlr2, N_NODES, 128);

  agg2_kernel<<<(N_NODES + 3) / 4, 256, 0, stream>>>(xlr2, att2, b2, offs, esrc, out2, N_NODES);

  pool_kernel<<<196, 256, 0, stream>>>(out2, batch, N_NODES, pooled, cnt);
  final_kernel<<<1, 64, 0, stream>>>(pooled, cnt, Wo, bo, out);
}